// Round 11
// baseline (211.946 us; speedup 1.0000x reference)
//
#include <hip/hip_runtime.h>
#include <hip/hip_fp16.h>
#include <cstdint>
#include <cmath>

#define NE 320000
#define NN 20000
#define NG 64
#define EPB 128   // edges per edge_gemm block

typedef __attribute__((ext_vector_type(8))) short s16x8;
typedef __attribute__((ext_vector_type(4))) float f32x4;

static __device__ __forceinline__ unsigned short f32_to_bf16(float x) {
    unsigned int u = __float_as_uint(x);
    u = (u + 0x7fffu + ((u >> 16) & 1u)) >> 16;
    return (unsigned short)u;
}
static __device__ __forceinline__ float bf16_to_f32(unsigned short h) {
    return __uint_as_float(((unsigned int)h) << 16);
}

// ---------------------------------------------------------------------------
// Setup: hA init (N*32), weight transpose/split (4096), deg=0, gsum/gcnt=0.
// NO device-scope fences anywhere in this build (R8/R9: ~150us each).
// ---------------------------------------------------------------------------
__global__ __launch_bounds__(256) void setup_kernel(
    const int* __restrict__ spec, const float* __restrict__ emb,
    float* __restrict__ hA,
    const float* __restrict__ w_r2,
    unsigned short* __restrict__ wt_hi, unsigned short* __restrict__ wt_lo,
    int* __restrict__ deg, float* __restrict__ gz)
{
    int t = blockIdx.x * 256 + threadIdx.x;
    if (t < NN * 32) hA[t] = emb[spec[t >> 5] * 32 + (t & 31)];
    if (t < 4096) {
        int c = t >> 6, k = t & 63;
        float v = w_r2[(c >= 32 ? 6144 : 0) + k * 96 + (c & 31)];
        unsigned short hb = f32_to_bf16(v);
        wt_hi[t] = hb;
        wt_lo[t] = f32_to_bf16(v - bf16_to_f32(hb));
    }
    if (t < NN) deg[t] = 0;
    if (t < 128) gz[t] = 0.0f;
}

// ---------------------------------------------------------------------------
__global__ __launch_bounds__(256) void count_kernel(
    const int* __restrict__ recv, int* __restrict__ deg)
{
    int e = blockIdx.x * 256 + threadIdx.x;
    atomicAdd(&deg[recv[e]], 1);
}

// ---------------------------------------------------------------------------
__global__ __launch_bounds__(1024) void scan_kernel(
    const int* __restrict__ deg,
    int* __restrict__ rowstart, int* __restrict__ cursor)
{
    __shared__ int tsum[1024];
    const int tid = threadIdx.x;
    const int PER = (NN + 1023) / 1024;   // 20
    const int base = tid * PER;

    int s = 0;
    for (int i = 0; i < PER; ++i) {
        int idx = base + i;
        if (idx < NN) s += deg[idx];
    }
    tsum[tid] = s;
    __syncthreads();
    for (int off = 1; off < 1024; off <<= 1) {
        int v = (tid >= off) ? tsum[tid - off] : 0;
        __syncthreads();
        tsum[tid] += v;
        __syncthreads();
    }
    int run = tsum[tid] - s;
    for (int i = 0; i < PER; ++i) {
        int idx = base + i;
        if (idx < NN) {
            rowstart[idx] = run;
            cursor[idx] = run;
            run += deg[idx];
        }
    }
    if (tid == 1023) rowstart[NN] = NE;
}

// ---------------------------------------------------------------------------
__global__ __launch_bounds__(256) void scatter_kernel(
    const int* __restrict__ recv, const int* __restrict__ snd,
    int* __restrict__ cursor, int* __restrict__ eidp, int* __restrict__ esnd)
{
    int e = blockIdx.x * 256 + threadIdx.x;
    int slot = atomicAdd(&cursor[recv[e]], 1);
    eidp[slot] = e;
    esnd[slot] = snd[e];
}

// ---------------------------------------------------------------------------
// Slot-ordered edge kernel, 128 edges/block (LDS 36 KB -> 4 blocks/CU).
// Two threads per edge split the 64-j radial MLP; 4 waves x 2 row-tiles MFMA.
// ---------------------------------------------------------------------------
__global__ __launch_bounds__(256) void edge_gemm_kernel(
    const float* __restrict__ vectors,
    const float* __restrict__ w_r1,    // 8 x 64
    const float* __restrict__ b_r1,    // 64
    const unsigned short* __restrict__ wt_hi,  // [64][64] bf16
    const unsigned short* __restrict__ wt_lo,  // [64][64] bf16
    const int* __restrict__ eidp,
    __half* __restrict__ rw0_0,        // [E][32] fp16, CSR order
    __half* __restrict__ rw0_1)        // [E][32] fp16, CSR order
{
    __shared__ __attribute__((aligned(16))) short sh_hi[EPB * 72];
    __shared__ __attribute__((aligned(16))) short sh_lo[EPB * 72];

    const int tid = threadIdx.x;
    const int ei  = tid & (EPB - 1);       // edge row in block
    const int jh  = tid >> 7;              // which half of j-range
    const int slot = blockIdx.x * EPB + ei;
    const int e = eidp[slot];

    float x = vectors[3 * e + 0];
    float y = vectors[3 * e + 1];
    float z = vectors[3 * e + 2];
    float r2 = x * x + y * y + z * z;
    float r = (r2 == 0.0f) ? 0.0f : sqrtf(r2);
    float rs = fmaxf(r, 1e-6f);
    float u = fminf(r * 0.2f, 1.0f);
    float env = (1.0f - u) * (1.0f - u) * (1.0f + 2.0f * u);
    float pref = 0.6324555320336759f * env / rs;
    float theta = 0.6283185307179586f * rs;

    float s1 = __sinf(theta), c1 = __cosf(theta);
    float twoc = 2.0f * c1;
    float b[8];
    {
        float sp = 0.0f, s = s1;
#pragma unroll
        for (int n = 0; n < 8; ++n) {
            b[n] = pref * s;
            float nx = twoc * s - sp;
            sp = s; s = nx;
        }
    }

    // this thread computes j = jh*32 .. jh*32+31
#pragma unroll
    for (int j0 = 0; j0 < 32; j0 += 8) {
        short hibuf[8], lobuf[8];
#pragma unroll
        for (int jj = 0; jj < 8; ++jj) {
            int j = jh * 32 + j0 + jj;
            float pre = b_r1[j];
#pragma unroll
            for (int n = 0; n < 8; ++n) pre = fmaf(b[n], w_r1[n * 64 + j], pre);
            float rj = pre * __builtin_amdgcn_rcpf(1.0f + __expf(-pre));
            unsigned short hb = f32_to_bf16(rj);
            float lov = rj - bf16_to_f32(hb);
            hibuf[jj] = (short)hb;
            lobuf[jj] = (short)f32_to_bf16(lov);
        }
        *(s16x8*)&sh_hi[ei * 72 + jh * 32 + j0] =
            (s16x8){hibuf[0],hibuf[1],hibuf[2],hibuf[3],hibuf[4],hibuf[5],hibuf[6],hibuf[7]};
        *(s16x8*)&sh_lo[ei * 72 + jh * 32 + j0] =
            (s16x8){lobuf[0],lobuf[1],lobuf[2],lobuf[3],lobuf[4],lobuf[5],lobuf[6],lobuf[7]};
    }

    __syncthreads();

    const int wv = tid >> 6;         // wave 0..3 handles rows wv*32..wv*32+31
    const int l = tid & 63;
    const int lrow = l & 15;
    const int lk = l >> 4;

    s16x8 Bhi[4][2], Blo[4][2];
#pragma unroll
    for (int ct = 0; ct < 4; ++ct)
#pragma unroll
        for (int kt = 0; kt < 2; ++kt) {
            int col = ct * 16 + lrow;
            int kof = kt * 32 + lk * 8;
            Bhi[ct][kt] = *(const s16x8*)(wt_hi + col * 64 + kof);
            Blo[ct][kt] = *(const s16x8*)(wt_lo + col * 64 + kof);
        }

    f32x4 acc[2][4];
#pragma unroll
    for (int rt = 0; rt < 2; ++rt)
#pragma unroll
        for (int ct = 0; ct < 4; ++ct) acc[rt][ct] = (f32x4){0.f, 0.f, 0.f, 0.f};

#pragma unroll
    for (int rt = 0; rt < 2; ++rt) {
        int row = wv * 32 + rt * 16 + lrow;
#pragma unroll
        for (int kt = 0; kt < 2; ++kt) {
            s16x8 ahi = *(const s16x8*)&sh_hi[row * 72 + kt * 32 + lk * 8];
            s16x8 alo = *(const s16x8*)&sh_lo[row * 72 + kt * 32 + lk * 8];
#pragma unroll
            for (int ct = 0; ct < 4; ++ct) {
                acc[rt][ct] = __builtin_amdgcn_mfma_f32_16x16x32_bf16(ahi, Bhi[ct][kt], acc[rt][ct], 0, 0, 0);
                acc[rt][ct] = __builtin_amdgcn_mfma_f32_16x16x32_bf16(alo, Bhi[ct][kt], acc[rt][ct], 0, 0, 0);
                acc[rt][ct] = __builtin_amdgcn_mfma_f32_16x16x32_bf16(ahi, Blo[ct][kt], acc[rt][ct], 0, 0, 0);
            }
        }
    }

    // repack to fp16 in LDS (reuse sh_hi: [128][72] halfs = 18.4 KB)
    __syncthreads();
    __half* stg = (__half*)sh_hi;
#pragma unroll
    for (int rt = 0; rt < 2; ++rt)
#pragma unroll
        for (int ct = 0; ct < 4; ++ct) {
            int col = ct * 16 + lrow;
#pragma unroll
            for (int rr = 0; rr < 4; ++rr) {
                int erow = wv * 32 + rt * 16 + lk * 4 + rr;
                stg[erow * 72 + col] = __float2half_rn(acc[rt][ct][rr]);
            }
        }
    __syncthreads();
    {
        // threads 0..127 write layer0 rows, 128..255 write layer1 rows
        const s16x8* src = (const s16x8*)&stg[ei * 72 + jh * 32];
        __half* dstp = (jh == 0 ? rw0_0 : rw0_1) + (size_t)slot * 32;
        s16x8* d = (s16x8*)dstp;
        d[0] = src[0]; d[1] = src[1]; d[2] = src[2]; d[3] = src[3];
    }
}

// ---------------------------------------------------------------------------
// One WAVE per node: halves split the edge gather by parity (depth ~8) and
// the 32-step update matvec (16 steps each), combined via shfl_xor(32).
// Returns outv (valid in ALL 64 lanes; channel = lane&31).
// ---------------------------------------------------------------------------
__device__ __forceinline__ float agg_update_val(
    const __half* __restrict__ rw0h, const float* __restrict__ hin,
    const int* __restrict__ rowstart, const int* __restrict__ esnd,
    const int* __restrict__ spec,
    const float* __restrict__ wmix0, const float* __restrict__ wscl,
    int n, int c, int kh, int half)
{
    int s0 = rowstart[n], s1 = rowstart[n + 1];
    float hv = hin[(size_t)n * 32 + c];

    float p0 = 0.f, p1 = 0.f, p2 = 0.f, p3 = 0.f;
    int k = s0 + kh;
    for (; k + 6 < s1; k += 8) {
        int sA = esnd[k], sB = esnd[k + 2], sC = esnd[k + 4], sD = esnd[k + 6];
        float rA = __half2float(rw0h[(size_t)k * 32 + c]);
        float rB = __half2float(rw0h[(size_t)(k + 2) * 32 + c]);
        float rC = __half2float(rw0h[(size_t)(k + 4) * 32 + c]);
        float rD = __half2float(rw0h[(size_t)(k + 6) * 32 + c]);
        float hA = hin[(size_t)sA * 32 + c];
        float hB = hin[(size_t)sB * 32 + c];
        float hC = hin[(size_t)sC * 32 + c];
        float hD = hin[(size_t)sD * 32 + c];
        p0 = fmaf(rA, hA, p0);
        p1 = fmaf(rB, hB, p1);
        p2 = fmaf(rC, hC, p2);
        p3 = fmaf(rD, hD, p3);
    }
    for (; k < s1; k += 2)
        p0 = fmaf(__half2float(rw0h[(size_t)k * 32 + c]),
                  hin[(size_t)esnd[k] * 32 + c], p0);
    float acc = (p0 + p1) + (p2 + p3);
    acc += __shfl_xor(acc, 32);            // full agg in both halves

    // update matvec: half kh handles cp = kh*16 .. kh*16+15 (2 chains each)
    const float* wsc = wscl + spec[n] * 1024;
    float m0 = 0.f, m1 = 0.f, q0 = 0.f, q1 = 0.f;
#pragma unroll
    for (int i = 0; i < 16; i += 2) {
        int cp = kh * 16 + i;
        float av0 = __shfl(acc, half + cp);
        float hb0 = __shfl(hv, half + cp);
        float av1 = __shfl(acc, half + cp + 1);
        float hb1 = __shfl(hv, half + cp + 1);
        m0 = fmaf(av0, wmix0[cp * 32 + c], m0);
        q0 = fmaf(hb0, wsc[cp * 32 + c], q0);
        m1 = fmaf(av1, wmix0[(cp + 1) * 32 + c], m1);
        q1 = fmaf(hb1, wsc[(cp + 1) * 32 + c], q1);
    }
    float upd = (m0 + m1) + (q0 + q1);
    upd += __shfl_xor(upd, 32);            // combine the two cp-halves
    return hv + upd;
}

// ---------------------------------------------------------------------------
// Layer 0: grid = NN*64 threads (one wave per node).
// ---------------------------------------------------------------------------
__global__ __launch_bounds__(256) void agg_update_kernel(
    const __half* __restrict__ rw0h, const float* __restrict__ hin,
    const int* __restrict__ rowstart, const int* __restrict__ esnd,
    const int* __restrict__ spec,
    const float* __restrict__ wmix0, const float* __restrict__ wscl,
    float* __restrict__ hout)
{
    int t = blockIdx.x * 256 + threadIdx.x;
    int n = t >> 6;
    int lane = threadIdx.x & 63;
    int c = lane & 31, kh = lane >> 5, half = lane & 32;
    float outv = agg_update_val(rw0h, hin, rowstart, esnd, spec, wmix0, wscl,
                                n, c, kh, half);
    if (kh == 0) hout[(size_t)n * 32 + c] = outv;
}

// ---------------------------------------------------------------------------
// Layer 1 + readout (wave-wide 4-way-split matvecs) + block-merged atomics.
// ---------------------------------------------------------------------------
__global__ __launch_bounds__(256) void agg_readout_kernel(
    const __half* __restrict__ rw0h, const float* __restrict__ hin,
    const int* __restrict__ rowstart, const int* __restrict__ esnd,
    const int* __restrict__ spec,
    const float* __restrict__ wmix0, const float* __restrict__ wscl,
    const int* __restrict__ gid_arr,
    const float* __restrict__ w_ro,
    const float* __restrict__ gamma, const float* __restrict__ beta,
    const float* __restrict__ w_h1, const float* __restrict__ b_h1,
    const float* __restrict__ w_h2, const float* __restrict__ b_h2,
    float* __restrict__ gsum, float* __restrict__ gcnt)
{
    __shared__ int sgid[4];
    __shared__ float sval[4];

    int t = blockIdx.x * 256 + threadIdx.x;
    int n = t >> 6;
    int lane = threadIdx.x & 63;
    int c = lane & 31, kh = lane >> 5, half = lane & 32;

    float outv = agg_update_val(rw0h, hin, rowstart, esnd, spec, wmix0, wscl,
                                n, c, kh, half);

    // readout 32->16: lane handles o = lane&15; quarter q4 = lane>>4 covers
    // cp = q4*8 .. q4*8+7 (2 chains); reduce quarters via xor 16, 32.
    int o = lane & 15;
    int q4 = lane >> 4;
    float r0 = 0.f, r1 = 0.f;
#pragma unroll
    for (int i = 0; i < 8; i += 2) {
        int cp = q4 * 8 + i;
        r0 = fmaf(__shfl(outv, cp),     w_ro[cp * 16 + o],       r0);
        r1 = fmaf(__shfl(outv, cp + 1), w_ro[(cp + 1) * 16 + o], r1);
    }
    float ro = r0 + r1;
    ro += __shfl_xor(ro, 16);
    ro += __shfl_xor(ro, 32);              // full ro[o] in every lane

    // LayerNorm over 16 (within aligned 16-lane groups; all groups identical)
    float ssum = ro;
#pragma unroll
    for (int m = 1; m < 16; m <<= 1) ssum += __shfl_xor(ssum, m);
    float mu = ssum * (1.0f / 16.0f);
    float d = ro - mu;
    float vs = d * d;
#pragma unroll
    for (int m = 1; m < 16; m <<= 1) vs += __shfl_xor(vs, m);
    float inv = rsqrtf(vs * (1.0f / 16.0f) + 1e-6f);
    float nrm = d * inv * gamma[o] + beta[o];

    // hidden 16->64: lane j = lane handles one unit (2 chains of 8)
    int j = lane;
    float a0 = b_h1[j], a1 = 0.f;
#pragma unroll
    for (int oo = 0; oo < 16; oo += 2) {
        a0 = fmaf(__shfl(nrm, oo),     w_h1[oo * 64 + j],       a0);
        a1 = fmaf(__shfl(nrm, oo + 1), w_h1[(oo + 1) * 64 + j], a1);
    }
    float a = a0 + a1;
    // gelu(a) = a * sigmoid(1.5957691216*(a + 0.044715 a^3))
    float g = a * __builtin_amdgcn_rcpf(
        1.0f + __expf(-1.5957691216057308f * (a + 0.044715f * a * a * a)));
    float partial = g * w_h2[j];
#pragma unroll
    for (int m = 1; m < 64; m <<= 1) partial += __shfl_xor(partial, m);

    // block-level merge (4 nodes/block, gid sorted)
    if (lane == 0) {
        int wv = threadIdx.x >> 6;
        sgid[wv] = gid_arr[n];
        sval[wv] = partial + b_h2[0];
    }
    __syncthreads();
    if (threadIdx.x == 0) {
        int g0 = sgid[0];
        float accv = sval[0];
        float cnt = 1.0f;
        for (int i = 1; i < 4; ++i) {
            if (sgid[i] == g0) { accv += sval[i]; cnt += 1.0f; }
            else {
                atomicAdd(&gsum[g0], accv);
                atomicAdd(&gcnt[g0], cnt);
                g0 = sgid[i]; accv = sval[i]; cnt = 1.0f;
            }
        }
        atomicAdd(&gsum[g0], accv);
        atomicAdd(&gcnt[g0], cnt);
    }
}

// ---------------------------------------------------------------------------
__global__ void finalize_kernel(const float* __restrict__ gsum,
                                const float* __restrict__ gcnt,
                                const float* __restrict__ scale,
                                const float* __restrict__ shift,
                                float* __restrict__ out)
{
    int g = threadIdx.x;
    if (g < NG) out[g] = gsum[g] / fmaxf(gcnt[g], 1.0f) * scale[0] + shift[0];
}

// ---------------------------------------------------------------------------
extern "C" void kernel_launch(void* const* d_in, const int* in_sizes, int n_in,
                              void* d_out, int out_size, void* d_ws, size_t ws_size,
                              hipStream_t stream)
{
    const float* vectors       = (const float*)d_in[0];
    const int*   node_species  = (const int*)d_in[1];
    const int*   senders       = (const int*)d_in[2];
    const int*   receivers     = (const int*)d_in[3];
    const int*   graph_id      = (const int*)d_in[4];
    const float* species_embed = (const float*)d_in[5];
    const float* w_r1          = (const float*)d_in[6];
    const float* b_r1          = (const float*)d_in[7];
    const float* w_r2          = (const float*)d_in[8];
    const float* w_mix         = (const float*)d_in[9];
    const float* w_sc          = (const float*)d_in[10];
    const float* w_ro          = (const float*)d_in[11];
    const float* ln_gamma      = (const float*)d_in[12];
    const float* ln_beta       = (const float*)d_in[13];
    const float* w_h1          = (const float*)d_in[14];
    const float* b_h1          = (const float*)d_in[15];
    const float* w_h2          = (const float*)d_in[16];
    const float* b_h2          = (const float*)d_in[17];
    const float* scale         = (const float*)d_in[18];
    const float* shift         = (const float*)d_in[19];
    float* out = (float*)d_out;

    // workspace layout
    __half* rw0_0 = (__half*)d_ws;                       // E*32 halfs (CSR order)
    __half* rw0_1 = rw0_0 + (size_t)NE * 32;             // E*32 halfs (CSR order)
    float* hA     = (float*)(rw0_1 + (size_t)NE * 32);   // N*32
    float* hB     = hA + (size_t)NN * 32;                // N*32
    float* gsum   = hB + (size_t)NN * 32;                // 64
    float* gcnt   = gsum + NG;                           // 64
    unsigned short* wt_hi = (unsigned short*)(gcnt + NG);  // 4096
    unsigned short* wt_lo = wt_hi + 4096;                  // 4096
    int* deg      = (int*)(wt_lo + 4096);                // N
    int* rowstart = deg + NN;                            // N+1
    int* cursor   = rowstart + NN + 1;                   // N (+pad)
    int* eidp     = cursor + NN + 1;                     // E
    int* esnd     = eidp + NE;                           // E

    setup_kernel<<<(NN * 32 + 255) / 256, 256, 0, stream>>>(
        node_species, species_embed, hA, w_r2, wt_hi, wt_lo, deg, gsum);

    count_kernel<<<NE / 256, 256, 0, stream>>>(receivers, deg);

    scan_kernel<<<1, 1024, 0, stream>>>(deg, rowstart, cursor);

    scatter_kernel<<<NE / 256, 256, 0, stream>>>(
        receivers, senders, cursor, eidp, esnd);

    edge_gemm_kernel<<<NE / EPB, 256, 0, stream>>>(
        vectors, w_r1, b_r1, wt_hi, wt_lo, eidp, rw0_0, rw0_1);

    agg_update_kernel<<<(NN * 64) / 256, 256, 0, stream>>>(
        rw0_0, hA, rowstart, esnd, node_species, w_mix, w_sc, hB);

    agg_readout_kernel<<<(NN * 64) / 256, 256, 0, stream>>>(
        rw0_1, hB, rowstart, esnd, node_species, w_mix + 3072, w_sc + 65536,
        graph_id, w_ro, ln_gamma, ln_beta, w_h1, b_h1, w_h2, b_h2, gsum, gcnt);

    finalize_kernel<<<1, 64, 0, stream>>>(gsum, gcnt, scale, shift, out);
}

// Round 12
// 162.995 us; speedup vs baseline: 1.3003x; 1.3003x over previous
//
#include <hip/hip_runtime.h>
#include <hip/hip_fp16.h>
#include <cstdint>
#include <cmath>

#define NE 320000
#define NN 20000
#define NG 64

typedef __attribute__((ext_vector_type(8))) short s16x8;
typedef __attribute__((ext_vector_type(4))) float f32x4;

static __device__ __forceinline__ unsigned short f32_to_bf16(float x) {
    unsigned int u = __float_as_uint(x);
    u = (u + 0x7fffu + ((u >> 16) & 1u)) >> 16;
    return (unsigned short)u;
}
static __device__ __forceinline__ float bf16_to_f32(unsigned short h) {
    return __uint_as_float(((unsigned int)h) << 16);
}

// ---------------------------------------------------------------------------
// Setup: hA init (N*32), weight transpose/split (4096), deg=0, gsum/gcnt=0.
// NO device-scope fences anywhere in this build (R8/R9 lesson: ~150us each).
// ---------------------------------------------------------------------------
__global__ __launch_bounds__(256) void setup_kernel(
    const int* __restrict__ spec, const float* __restrict__ emb,
    float* __restrict__ hA,
    const float* __restrict__ w_r2,
    unsigned short* __restrict__ wt_hi, unsigned short* __restrict__ wt_lo,
    int* __restrict__ deg, float* __restrict__ gz)
{
    int t = blockIdx.x * 256 + threadIdx.x;
    if (t < NN * 32) hA[t] = emb[spec[t >> 5] * 32 + (t & 31)];
    if (t < 4096) {
        int c = t >> 6, k = t & 63;
        float v = w_r2[(c >= 32 ? 6144 : 0) + k * 96 + (c & 31)];
        unsigned short hb = f32_to_bf16(v);
        wt_hi[t] = hb;
        wt_lo[t] = f32_to_bf16(v - bf16_to_f32(hb));
    }
    if (t < NN) deg[t] = 0;
    if (t < 128) gz[t] = 0.0f;
}

// ---------------------------------------------------------------------------
__global__ __launch_bounds__(256) void count_kernel(
    const int* __restrict__ recv, int* __restrict__ deg)
{
    int e = blockIdx.x * 256 + threadIdx.x;
    atomicAdd(&deg[recv[e]], 1);
}

// ---------------------------------------------------------------------------
// Single-block exclusive scan of deg[NN] -> rowstart/cursor.
// ---------------------------------------------------------------------------
__global__ __launch_bounds__(1024) void scan_kernel(
    const int* __restrict__ deg,
    int* __restrict__ rowstart, int* __restrict__ cursor)
{
    __shared__ int tsum[1024];
    const int tid = threadIdx.x;
    const int PER = (NN + 1023) / 1024;   // 20
    const int base = tid * PER;

    int s = 0;
    for (int i = 0; i < PER; ++i) {
        int idx = base + i;
        if (idx < NN) s += deg[idx];
    }
    tsum[tid] = s;
    __syncthreads();
    for (int off = 1; off < 1024; off <<= 1) {
        int v = (tid >= off) ? tsum[tid - off] : 0;
        __syncthreads();
        tsum[tid] += v;
        __syncthreads();
    }
    int run = tsum[tid] - s;
    for (int i = 0; i < PER; ++i) {
        int idx = base + i;
        if (idx < NN) {
            rowstart[idx] = run;
            cursor[idx] = run;
            run += deg[idx];
        }
    }
    if (tid == 1023) rowstart[NN] = NE;
}

// ---------------------------------------------------------------------------
// Edge-ordered edge kernel with INLINE scatter: thread = edge e (vectors read
// coalesced); slot = atomicAdd(cursor[recv[e]]); records esnd[slot]; writes
// rw0 rows at slot (scattered 64B stores, fire-and-forget). R7-bench pattern.
// 256 edges/block, 72 KB LDS.
// ---------------------------------------------------------------------------
__global__ __launch_bounds__(256) void edge_gemm_kernel(
    const float* __restrict__ vectors,
    const float* __restrict__ w_r1,    // 8 x 64
    const float* __restrict__ b_r1,    // 64
    const unsigned short* __restrict__ wt_hi,  // [64][64] bf16
    const unsigned short* __restrict__ wt_lo,  // [64][64] bf16
    const int* __restrict__ recv, const int* __restrict__ snd,
    int* __restrict__ cursor, int* __restrict__ esnd,
    __half* __restrict__ rw0_0,        // [E][32] fp16, CSR order
    __half* __restrict__ rw0_1)        // [E][32] fp16, CSR order
{
    __shared__ __attribute__((aligned(16))) short sh_hi[256 * 72];
    __shared__ __attribute__((aligned(16))) short sh_lo[256 * 72];

    const int tid = threadIdx.x;
    const int e = blockIdx.x * 256 + tid;

    // inline scatter: grab CSR slot, record sender
    const int slot = atomicAdd(&cursor[recv[e]], 1);
    esnd[slot] = snd[e];

    float x = vectors[3 * e + 0];
    float y = vectors[3 * e + 1];
    float z = vectors[3 * e + 2];
    float r2 = x * x + y * y + z * z;
    float r = (r2 == 0.0f) ? 0.0f : sqrtf(r2);
    float rs = fmaxf(r, 1e-6f);
    float u = fminf(r * 0.2f, 1.0f);
    float env = (1.0f - u) * (1.0f - u) * (1.0f + 2.0f * u);
    float pref = 0.6324555320336759f * env / rs;
    float theta = 0.6283185307179586f * rs;

    float s1 = __sinf(theta), c1 = __cosf(theta);
    float twoc = 2.0f * c1;
    float b[8];
    {
        float sp = 0.0f, s = s1;
#pragma unroll
        for (int n = 0; n < 8; ++n) {
            b[n] = pref * s;
            float nx = twoc * s - sp;
            sp = s; s = nx;
        }
    }

#pragma unroll
    for (int j0 = 0; j0 < 64; j0 += 8) {
        short hibuf[8], lobuf[8];
#pragma unroll
        for (int jj = 0; jj < 8; ++jj) {
            int j = j0 + jj;
            float pre = b_r1[j];
#pragma unroll
            for (int n = 0; n < 8; ++n) pre = fmaf(b[n], w_r1[n * 64 + j], pre);
            float rj = pre * __builtin_amdgcn_rcpf(1.0f + __expf(-pre));
            unsigned short hb = f32_to_bf16(rj);
            float lov = rj - bf16_to_f32(hb);
            hibuf[jj] = (short)hb;
            lobuf[jj] = (short)f32_to_bf16(lov);
        }
        *(s16x8*)&sh_hi[tid * 72 + j0] =
            (s16x8){hibuf[0],hibuf[1],hibuf[2],hibuf[3],hibuf[4],hibuf[5],hibuf[6],hibuf[7]};
        *(s16x8*)&sh_lo[tid * 72 + j0] =
            (s16x8){lobuf[0],lobuf[1],lobuf[2],lobuf[3],lobuf[4],lobuf[5],lobuf[6],lobuf[7]};
    }

    __syncthreads();

    const int wv = tid >> 6;
    const int l = tid & 63;
    const int lrow = l & 15;
    const int lk = l >> 4;

    s16x8 Bhi[4][2], Blo[4][2];
#pragma unroll
    for (int ct = 0; ct < 4; ++ct)
#pragma unroll
        for (int kt = 0; kt < 2; ++kt) {
            int col = ct * 16 + lrow;
            int kof = kt * 32 + lk * 8;
            Bhi[ct][kt] = *(const s16x8*)(wt_hi + col * 64 + kof);
            Blo[ct][kt] = *(const s16x8*)(wt_lo + col * 64 + kof);
        }

    f32x4 acc[4][4];
#pragma unroll
    for (int rt = 0; rt < 4; ++rt)
#pragma unroll
        for (int ct = 0; ct < 4; ++ct) acc[rt][ct] = (f32x4){0.f, 0.f, 0.f, 0.f};

#pragma unroll
    for (int rt = 0; rt < 4; ++rt) {
        int row = wv * 64 + rt * 16 + lrow;
#pragma unroll
        for (int kt = 0; kt < 2; ++kt) {
            s16x8 ahi = *(const s16x8*)&sh_hi[row * 72 + kt * 32 + lk * 8];
            s16x8 alo = *(const s16x8*)&sh_lo[row * 72 + kt * 32 + lk * 8];
#pragma unroll
            for (int ct = 0; ct < 4; ++ct) {
                acc[rt][ct] = __builtin_amdgcn_mfma_f32_16x16x32_bf16(ahi, Bhi[ct][kt], acc[rt][ct], 0, 0, 0);
                acc[rt][ct] = __builtin_amdgcn_mfma_f32_16x16x32_bf16(alo, Bhi[ct][kt], acc[rt][ct], 0, 0, 0);
                acc[rt][ct] = __builtin_amdgcn_mfma_f32_16x16x32_bf16(ahi, Blo[ct][kt], acc[rt][ct], 0, 0, 0);
            }
        }
    }

    // repack to fp16 in LDS (row stride 72 halfs = 144B, 16B-aligned)
    __syncthreads();
    __half* stg = (__half*)sh_hi;
#pragma unroll
    for (int rt = 0; rt < 4; ++rt)
#pragma unroll
        for (int ct = 0; ct < 4; ++ct) {
            int col = ct * 16 + lrow;
#pragma unroll
            for (int rr = 0; rr < 4; ++rr) {
                int erow = wv * 64 + rt * 16 + lk * 4 + rr;
                stg[erow * 72 + col] = __float2half_rn(acc[rt][ct][rr]);
            }
        }
    __syncthreads();
    {
        const s16x8* src = (const s16x8*)&sh_hi[tid * 72];
        size_t sb = (size_t)slot * 32;
        s16x8* d0 = (s16x8*)(rw0_0 + sb);
        s16x8* d1 = (s16x8*)(rw0_1 + sb);
        d0[0] = src[0]; d0[1] = src[1]; d0[2] = src[2]; d0[3] = src[3];
        d1[0] = src[4]; d1[1] = src[5]; d1[2] = src[6]; d1[3] = src[7];
    }
}

// ---------------------------------------------------------------------------
// CSR gather (sequential rw0 rows, direct esnd broadcast loads, 4-deep
// unroll) + node update (chain-split). Exact R7 structure (known fast).
// ---------------------------------------------------------------------------
__device__ __forceinline__ float agg_update_val(
    const __half* __restrict__ rw0h, const float* __restrict__ hin,
    const int* __restrict__ rowstart, const int* __restrict__ esnd,
    const int* __restrict__ spec,
    const float* __restrict__ wmix0, const float* __restrict__ wscl,
    int t, int n, int c, int half)
{
    int s0 = rowstart[n], s1 = rowstart[n + 1];
    float hv = hin[t];

    float p0 = 0.f, p1 = 0.f, p2 = 0.f, p3 = 0.f;
    int k = s0;
    for (; k + 4 <= s1; k += 4) {
        int sA = esnd[k], sB = esnd[k + 1], sC = esnd[k + 2], sD = esnd[k + 3];
        float rA = __half2float(rw0h[(size_t)k * 32 + c]);
        float rB = __half2float(rw0h[(size_t)(k + 1) * 32 + c]);
        float rC = __half2float(rw0h[(size_t)(k + 2) * 32 + c]);
        float rD = __half2float(rw0h[(size_t)(k + 3) * 32 + c]);
        float hA = hin[(size_t)sA * 32 + c];
        float hB = hin[(size_t)sB * 32 + c];
        float hC = hin[(size_t)sC * 32 + c];
        float hD = hin[(size_t)sD * 32 + c];
        p0 = fmaf(rA, hA, p0);
        p1 = fmaf(rB, hB, p1);
        p2 = fmaf(rC, hC, p2);
        p3 = fmaf(rD, hD, p3);
    }
    for (; k < s1; ++k)
        p0 = fmaf(__half2float(rw0h[(size_t)k * 32 + c]),
                  hin[(size_t)esnd[k] * 32 + c], p0);
    float acc = (p0 + p1) + (p2 + p3);

    const float* wsc = wscl + spec[n] * 1024;
    float m0 = 0.f, m1 = 0.f, q0 = 0.f, q1 = 0.f;
#pragma unroll
    for (int cp = 0; cp < 32; cp += 2) {
        float av0 = __shfl(acc, half + cp);
        float hb0 = __shfl(hv, half + cp);
        float av1 = __shfl(acc, half + cp + 1);
        float hb1 = __shfl(hv, half + cp + 1);
        m0 = fmaf(av0, wmix0[cp * 32 + c], m0);
        q0 = fmaf(hb0, wsc[cp * 32 + c], q0);
        m1 = fmaf(av1, wmix0[(cp + 1) * 32 + c], m1);
        q1 = fmaf(hb1, wsc[(cp + 1) * 32 + c], q1);
    }
    return hv + (m0 + m1) + (q0 + q1);
}

// ---------------------------------------------------------------------------
__global__ __launch_bounds__(256) void agg_update_kernel(
    const __half* __restrict__ rw0h, const float* __restrict__ hin,
    const int* __restrict__ rowstart, const int* __restrict__ esnd,
    const int* __restrict__ spec,
    const float* __restrict__ wmix0, const float* __restrict__ wscl,
    float* __restrict__ hout)
{
    int t = blockIdx.x * 256 + threadIdx.x;   // grid = NN*32 exactly
    int n = t >> 5, c = t & 31;
    int half = (threadIdx.x & 63) & 32;
    hout[t] = agg_update_val(rw0h, hin, rowstart, esnd, spec, wmix0, wscl,
                             t, n, c, half);
}

// ---------------------------------------------------------------------------
// Layer 1 + readout fused, chain-split, block-reduced atomics. NO fence.
// ---------------------------------------------------------------------------
__global__ __launch_bounds__(256) void agg_readout_kernel(
    const __half* __restrict__ rw0h, const float* __restrict__ hin,
    const int* __restrict__ rowstart, const int* __restrict__ esnd,
    const int* __restrict__ spec,
    const float* __restrict__ wmix0, const float* __restrict__ wscl,
    const int* __restrict__ gid_arr,
    const float* __restrict__ w_ro,
    const float* __restrict__ gamma, const float* __restrict__ beta,
    const float* __restrict__ w_h1, const float* __restrict__ b_h1,
    const float* __restrict__ w_h2, const float* __restrict__ b_h2,
    float* __restrict__ gsum, float* __restrict__ gcnt)
{
    __shared__ int sgid[8];
    __shared__ float sval[8];

    int t = blockIdx.x * 256 + threadIdx.x;   // grid = NN*32 exactly
    int n = t >> 5, c = t & 31;
    int half = (threadIdx.x & 63) & 32;

    float outv = agg_update_val(rw0h, hin, rowstart, esnd, spec, wmix0, wscl,
                                t, n, c, half);

    // readout 32->16 (4 chains)
    int o = c & 15;
    float r0 = 0.f, r1 = 0.f, r2 = 0.f, r3 = 0.f;
#pragma unroll
    for (int cp = 0; cp < 32; cp += 4) {
        r0 = fmaf(__shfl(outv, half + cp),     w_ro[cp * 16 + o],       r0);
        r1 = fmaf(__shfl(outv, half + cp + 1), w_ro[(cp + 1) * 16 + o], r1);
        r2 = fmaf(__shfl(outv, half + cp + 2), w_ro[(cp + 2) * 16 + o], r2);
        r3 = fmaf(__shfl(outv, half + cp + 3), w_ro[(cp + 3) * 16 + o], r3);
    }
    float ro = (r0 + r1) + (r2 + r3);

    // LayerNorm over 16 (aligned 16-lane groups)
    float ssum = ro;
#pragma unroll
    for (int m = 1; m < 16; m <<= 1) ssum += __shfl_xor(ssum, m);
    float mu = ssum * (1.0f / 16.0f);
    float d = ro - mu;
    float vs = d * d;
#pragma unroll
    for (int m = 1; m < 16; m <<= 1) vs += __shfl_xor(vs, m);
    float inv = rsqrtf(vs * (1.0f / 16.0f) + 1e-6f);
    float nrm = d * inv * gamma[o] + beta[o];

    // hidden 16->64: lane c handles units c and c+32 (4 chains)
    int j1 = c, j2 = c + 32;
    float a1a = b_h1[j1], a1b = 0.f, a2a = b_h1[j2], a2b = 0.f;
#pragma unroll
    for (int oo = 0; oo < 16; oo += 2) {
        float nv0 = __shfl(nrm, half + oo);
        float nv1 = __shfl(nrm, half + oo + 1);
        a1a = fmaf(nv0, w_h1[oo * 64 + j1], a1a);
        a2a = fmaf(nv0, w_h1[oo * 64 + j2], a2a);
        a1b = fmaf(nv1, w_h1[(oo + 1) * 64 + j1], a1b);
        a2b = fmaf(nv1, w_h1[(oo + 1) * 64 + j2], a2b);
    }
    float a1 = a1a + a1b, a2 = a2a + a2b;
    // gelu(a) = a * sigmoid(1.5957691216*(a + 0.044715 a^3))
    float g1 = a1 * __builtin_amdgcn_rcpf(
        1.0f + __expf(-1.5957691216057308f * (a1 + 0.044715f * a1 * a1 * a1)));
    float g2 = a2 * __builtin_amdgcn_rcpf(
        1.0f + __expf(-1.5957691216057308f * (a2 + 0.044715f * a2 * a2 * a2)));
    float partial = fmaf(g1, w_h2[j1], g2 * w_h2[j2]);
#pragma unroll
    for (int m = 1; m < 32; m <<= 1) partial += __shfl_xor(partial, m);

    // block-level merge (8 nodes, gid sorted)
    if (c == 0) {
        int hw = threadIdx.x >> 5;
        sgid[hw] = gid_arr[n];
        sval[hw] = partial + b_h2[0];
    }
    __syncthreads();
    if (threadIdx.x == 0) {
        int g0 = sgid[0];
        float accv = sval[0];
        float cnt = 1.0f;
        for (int i = 1; i < 8; ++i) {
            if (sgid[i] == g0) { accv += sval[i]; cnt += 1.0f; }
            else {
                atomicAdd(&gsum[g0], accv);
                atomicAdd(&gcnt[g0], cnt);
                g0 = sgid[i]; accv = sval[i]; cnt = 1.0f;
            }
        }
        atomicAdd(&gsum[g0], accv);
        atomicAdd(&gcnt[g0], cnt);
    }
}

// ---------------------------------------------------------------------------
__global__ void finalize_kernel(const float* __restrict__ gsum,
                                const float* __restrict__ gcnt,
                                const float* __restrict__ scale,
                                const float* __restrict__ shift,
                                float* __restrict__ out)
{
    int g = threadIdx.x;
    if (g < NG) out[g] = gsum[g] / fmaxf(gcnt[g], 1.0f) * scale[0] + shift[0];
}

// ---------------------------------------------------------------------------
extern "C" void kernel_launch(void* const* d_in, const int* in_sizes, int n_in,
                              void* d_out, int out_size, void* d_ws, size_t ws_size,
                              hipStream_t stream)
{
    const float* vectors       = (const float*)d_in[0];
    const int*   node_species  = (const int*)d_in[1];
    const int*   senders       = (const int*)d_in[2];
    const int*   receivers     = (const int*)d_in[3];
    const int*   graph_id      = (const int*)d_in[4];
    const float* species_embed = (const float*)d_in[5];
    const float* w_r1          = (const float*)d_in[6];
    const float* b_r1          = (const float*)d_in[7];
    const float* w_r2          = (const float*)d_in[8];
    const float* w_mix         = (const float*)d_in[9];
    const float* w_sc          = (const float*)d_in[10];
    const float* w_ro          = (const float*)d_in[11];
    const float* ln_gamma      = (const float*)d_in[12];
    const float* ln_beta       = (const float*)d_in[13];
    const float* w_h1          = (const float*)d_in[14];
    const float* b_h1          = (const float*)d_in[15];
    const float* w_h2          = (const float*)d_in[16];
    const float* b_h2          = (const float*)d_in[17];
    const float* scale         = (const float*)d_in[18];
    const float* shift         = (const float*)d_in[19];
    float* out = (float*)d_out;

    // workspace layout
    __half* rw0_0 = (__half*)d_ws;                       // E*32 halfs (CSR order)
    __half* rw0_1 = rw0_0 + (size_t)NE * 32;             // E*32 halfs (CSR order)
    float* hA     = (float*)(rw0_1 + (size_t)NE * 32);   // N*32
    float* hB     = hA + (size_t)NN * 32;                // N*32
    float* gsum   = hB + (size_t)NN * 32;                // 64
    float* gcnt   = gsum + NG;                           // 64
    unsigned short* wt_hi = (unsigned short*)(gcnt + NG);  // 4096
    unsigned short* wt_lo = wt_hi + 4096;                  // 4096
    int* deg      = (int*)(wt_lo + 4096);                // N
    int* rowstart = deg + NN;                            // N+1
    int* cursor   = rowstart + NN + 1;                   // N (+pad)
    int* esnd     = cursor + NN + 1;                     // E

    setup_kernel<<<(NN * 32 + 255) / 256, 256, 0, stream>>>(
        node_species, species_embed, hA, w_r2, wt_hi, wt_lo, deg, gsum);

    count_kernel<<<NE / 256, 256, 0, stream>>>(receivers, deg);

    scan_kernel<<<1, 1024, 0, stream>>>(deg, rowstart, cursor);

    edge_gemm_kernel<<<NE / 256, 256, 0, stream>>>(
        vectors, w_r1, b_r1, wt_hi, wt_lo, receivers, senders, cursor, esnd,
        rw0_0, rw0_1);

    agg_update_kernel<<<(NN * 32) / 256, 256, 0, stream>>>(
        rw0_0, hA, rowstart, esnd, node_species, w_mix, w_sc, hB);

    agg_readout_kernel<<<(NN * 32) / 256, 256, 0, stream>>>(
        rw0_1, hB, rowstart, esnd, node_species, w_mix + 3072, w_sc + 65536,
        graph_id, w_ro, ln_gamma, ln_beta, w_h1, b_h1, w_h2, b_h2, gsum, gcnt);

    finalize_kernel<<<1, 64, 0, stream>>>(gsum, gcnt, scale, shift, out);
}